// Round 19
// baseline (348.856 us; speedup 1.0000x reference)
//
#include <hip/hip_runtime.h>
#include <hip/hip_bf16.h>

#define B_SZ 2
#define S_SZ 2048
#define DIM_SZ 3072
#define H_SZ 24
#define D_SZ 128
#define EPS_LN 1e-6f

typedef __attribute__((ext_vector_type(8))) short short8;
typedef __attribute__((ext_vector_type(4))) float f32x4;
typedef __attribute__((ext_vector_type(16))) float f32x16;
typedef __attribute__((ext_vector_type(4))) unsigned int u32x4;
typedef unsigned short u16;

__device__ __forceinline__ float fexp2(float x) {
  return __builtin_amdgcn_exp2f(x);  // v_exp_f32 (native base-2)
}

__device__ __forceinline__ u16 f2bf(float f) {
  union { float f; unsigned u; } x; x.f = f;
  unsigned r = x.u + 0x7fffu + ((x.u >> 16) & 1u);  // RNE
  return (u16)(r >> 16);
}
__device__ __forceinline__ unsigned pack2(float a, float b) {
  return (unsigned)f2bf(a) | ((unsigned)f2bf(b) << 16);
}
__device__ __forceinline__ unsigned cvtpk(float a, float b) {
  unsigned r;
  asm("v_cvt_pk_bf16_f32 %0, %1, %2" : "=v"(r) : "v"(a), "v"(b));
  return r;
}

// async global->LDS, 16B per lane (wave-uniform LDS base + lane*16).
typedef const __attribute__((address_space(1))) void* gas_ptr;
typedef __attribute__((address_space(3))) void* las_ptr;
__device__ __forceinline__ void gload_lds16(const void* g, void* l) {
  __builtin_amdgcn_global_load_lds(
      reinterpret_cast<gas_ptr>(reinterpret_cast<uintptr_t>(g)),
      reinterpret_cast<las_ptr>(reinterpret_cast<uintptr_t>(l)), 16, 0, 0);
}

#define BAR()                              \
  {                                        \
    __builtin_amdgcn_sched_barrier(0);     \
    __builtin_amdgcn_s_barrier();          \
    __builtin_amdgcn_sched_barrier(0);     \
  }

// ---------------------------------------------------------------------------
// 256x256 deep-pipelined bf16 MFMA GEMM (round-12 validated config: fp32
// split C-write).  8 waves (2Mx4N), per-wave 128x64, BK=64, LDS 128KB,
// counted vmcnt(8).  cols < Nsplit -> C, else -> C2 (block-uniform).
// Stage of tile t+2 happens entirely at P3 (race-free proven config; the
// round-18 B-at-P2 split tripped the determinism check and was reverted).
// ---------------------------------------------------------------------------
__global__ __launch_bounds__(512, 2) void gemm256(const u16* __restrict__ A,
                                                  const u16* __restrict__ Bt,
                                                  float* __restrict__ C,
                                                  float* __restrict__ C2,
                                                  int M, int N, int Nsplit,
                                                  int K) {
  __shared__ u16 LDSb[2][2][256 * 64];  // [buf][A/B][row*64+k]  128 KB

  const int tid = threadIdx.x;
  const int l15 = tid & 15;
  const int lg = (tid >> 4) & 3;
  const int wv = tid >> 6;   // 0..7
  const int wm = wv >> 2;    // 0..1  (M half)
  const int wn = wv & 3;     // 0..3  (N quarter)

  const int nbx = N >> 8;
  int bid = (int)blockIdx.x;
  const int cpx = (int)gridDim.x >> 3;  // grid % 8 == 0 (bijective XCD swizzle)
  bid = (bid & 7) * cpx + (bid >> 3);
  const int row0 = (bid / nbx) * 256;
  const int col0 = (bid % nbx) * 256;

  size_t asrc[4], bsrc[4];
  int loff[4];
#pragma unroll
  for (int j = 0; j < 4; ++j) {
    const int o = (tid + j * 512) * 16;         // [0, 32768)
    const int r = o >> 7;                       // LDS row 0..255
    const int sb = (o & 127) ^ ((r & 7) << 4);  // swizzled byte-in-row
    loff[j] = o;
    asrc[j] = (size_t)(row0 + r) * K + (sb >> 1);
    bsrc[j] = (size_t)(col0 + r) * K + (sb >> 1);
  }
  const int xr = (l15 & 7) << 4;

  f32x4 acc[8][4];
#pragma unroll
  for (int m = 0; m < 8; ++m)
#pragma unroll
    for (int n = 0; n < 4; ++n) acc[m][n] = (f32x4)0.f;

  const int NT = K >> 6;

#define STAGE256(t)                                                         \
  {                                                                         \
    char* abL = (char*)&LDSb[(t) & 1][0][0];                                \
    char* bbL = (char*)&LDSb[(t) & 1][1][0];                                \
    _Pragma("unroll") for (int j = 0; j < 4; ++j)                           \
        gload_lds16(A + asrc[j] + (size_t)(t) * 64, abL + loff[j]);         \
    _Pragma("unroll") for (int j = 0; j < 4; ++j)                           \
        gload_lds16(Bt + bsrc[j] + (size_t)(t) * 64, bbL + loff[j]);        \
  }

  STAGE256(0);
  STAGE256(1);
  asm volatile("s_waitcnt vmcnt(8)" ::: "memory");
  BAR();

  short8 af[4][2];
  short8 bf[4][2];

  for (int t = 0; t < NT; ++t) {
    const char* ab = (const char*)&LDSb[t & 1][0][0];
    const char* bb = (const char*)&LDSb[t & 1][1][0];

    // P0: A(M-half0) + B(n0,n1); MFMA Q0
#pragma unroll
    for (int m = 0; m < 4; ++m)
#pragma unroll
      for (int kk = 0; kk < 2; ++kk)
        af[m][kk] = *(const short8*)(ab + (wm * 128 + m * 16 + l15) * 128 +
                                     ((kk * 64 + lg * 16) ^ xr));
#pragma unroll
    for (int n = 0; n < 2; ++n)
#pragma unroll
      for (int kk = 0; kk < 2; ++kk)
        bf[n][kk] = *(const short8*)(bb + (wn * 64 + n * 16 + l15) * 128 +
                                     ((kk * 64 + lg * 16) ^ xr));
    BAR();
    __builtin_amdgcn_s_setprio(1);
#pragma unroll
    for (int m = 0; m < 4; ++m)
#pragma unroll
      for (int n = 0; n < 2; ++n)
#pragma unroll
        for (int kk = 0; kk < 2; ++kk)
          acc[m][n] = __builtin_amdgcn_mfma_f32_16x16x32_bf16(
              af[m][kk], bf[n][kk], acc[m][n], 0, 0, 0);
    __builtin_amdgcn_s_setprio(0);
    BAR();

    // P1: B(n2,n3); MFMA Q1
#pragma unroll
    for (int n = 2; n < 4; ++n)
#pragma unroll
      for (int kk = 0; kk < 2; ++kk)
        bf[n][kk] = *(const short8*)(bb + (wn * 64 + n * 16 + l15) * 128 +
                                     ((kk * 64 + lg * 16) ^ xr));
    BAR();
    __builtin_amdgcn_s_setprio(1);
#pragma unroll
    for (int m = 0; m < 4; ++m)
#pragma unroll
      for (int n = 2; n < 4; ++n)
#pragma unroll
        for (int kk = 0; kk < 2; ++kk)
          acc[m][n] = __builtin_amdgcn_mfma_f32_16x16x32_bf16(
              af[m][kk], bf[n][kk], acc[m][n], 0, 0, 0);
    __builtin_amdgcn_s_setprio(0);
    BAR();

    // P2: A(M-half1); MFMA Q2
#pragma unroll
    for (int m = 0; m < 4; ++m)
#pragma unroll
      for (int kk = 0; kk < 2; ++kk)
        af[m][kk] = *(const short8*)(ab + (wm * 128 + 64 + m * 16 + l15) * 128 +
                                     ((kk * 64 + lg * 16) ^ xr));
    BAR();
    __builtin_amdgcn_s_setprio(1);
#pragma unroll
    for (int m = 0; m < 4; ++m)
#pragma unroll
      for (int n = 2; n < 4; ++n)
#pragma unroll
        for (int kk = 0; kk < 2; ++kk)
          acc[4 + m][n] = __builtin_amdgcn_mfma_f32_16x16x32_bf16(
              af[m][kk], bf[n][kk], acc[4 + m][n], 0, 0, 0);
    __builtin_amdgcn_s_setprio(0);
    BAR();

    // P3: stage t+2; MFMA Q3; counted vmcnt
    if (t + 2 < NT) STAGE256(t + 2);
    __builtin_amdgcn_s_setprio(1);
#pragma unroll
    for (int m = 0; m < 4; ++m)
#pragma unroll
      for (int n = 0; n < 2; ++n)
#pragma unroll
        for (int kk = 0; kk < 2; ++kk)
          acc[4 + m][n] = __builtin_amdgcn_mfma_f32_16x16x32_bf16(
              af[m][kk], bf[n][kk], acc[4 + m][n], 0, 0, 0);
    __builtin_amdgcn_s_setprio(0);
    if (t + 2 < NT) {
      asm volatile("s_waitcnt vmcnt(8)" ::: "memory");
    } else if (t + 1 < NT) {
      asm volatile("s_waitcnt vmcnt(0)" ::: "memory");
    }
    BAR();
  }

  const bool lo = (col0 < Nsplit);
  float* Cw = lo ? C : C2;
  const int cw = lo ? Nsplit : (N - Nsplit);
  const int cb = col0 - (lo ? 0 : Nsplit);
#pragma unroll
  for (int m = 0; m < 8; ++m)
#pragma unroll
    for (int n = 0; n < 4; ++n)
#pragma unroll
      for (int r = 0; r < 4; ++r)
        Cw[(size_t)(row0 + wm * 128 + m * 16 + lg * 4 + r) * cw + cb +
           wn * 64 + n * 16 + l15] = acc[m][n][r];
#undef STAGE256
}

// ---------------------------------------------------------------------------
// 256x192-tile 4-phase pipeline for N=3072 outputs (validated round-12):
// grid 16x16 = 256 blocks -> 100% CU coverage.  vmcnt(7) = 4A+3B loads/tile.
// ---------------------------------------------------------------------------
__global__ __launch_bounds__(512, 2) void gemm192(const u16* __restrict__ A,
                                                  const u16* __restrict__ Bt,
                                                  float* __restrict__ C,
                                                  int M, int N, int K) {
  __shared__ u16 LA[2][256 * 64];  // 64 KB
  __shared__ u16 LB[2][192 * 64];  // 48 KB

  const int tid = threadIdx.x;
  const int l15 = tid & 15;
  const int lg = (tid >> 4) & 3;
  const int wv = tid >> 6;
  const int wm = wv >> 2;   // 0..1
  const int wn = wv & 3;    // 0..3 -> 48-col strip

  const int nbx = N / 192;
  int bid = (int)blockIdx.x;
  const int cpx = (int)gridDim.x >> 3;
  bid = (bid & 7) * cpx + (bid >> 3);
  const int row0 = (bid / nbx) * 256;
  const int col0 = (bid % nbx) * 192;

  size_t asrc[4], bsrc[3];
  int aoff[4], boff[3];
#pragma unroll
  for (int j = 0; j < 4; ++j) {
    const int o = (tid + j * 512) * 16;  // [0, 32768)
    const int r = o >> 7;
    const int sb = (o & 127) ^ ((r & 7) << 4);
    aoff[j] = o;
    asrc[j] = (size_t)(row0 + r) * K + (sb >> 1);
  }
#pragma unroll
  for (int j = 0; j < 3; ++j) {
    const int o = (tid + j * 512) * 16;  // [0, 24576)
    const int r = o >> 7;                // 0..191
    const int sb = (o & 127) ^ ((r & 7) << 4);
    boff[j] = o;
    bsrc[j] = (size_t)(col0 + r) * K + (sb >> 1);
  }
  const int xr = (l15 & 7) << 4;

  f32x4 acc[8][3];
#pragma unroll
  for (int m = 0; m < 8; ++m)
#pragma unroll
    for (int n = 0; n < 3; ++n) acc[m][n] = (f32x4)0.f;

  const int NT = K >> 6;

#define STAGE192(t)                                                         \
  {                                                                         \
    char* abL = (char*)&LA[(t) & 1][0];                                     \
    char* bbL = (char*)&LB[(t) & 1][0];                                     \
    _Pragma("unroll") for (int j = 0; j < 4; ++j)                           \
        gload_lds16(A + asrc[j] + (size_t)(t) * 64, abL + aoff[j]);         \
    _Pragma("unroll") for (int j = 0; j < 3; ++j)                           \
        gload_lds16(Bt + bsrc[j] + (size_t)(t) * 64, bbL + boff[j]);        \
  }

  STAGE192(0);
  STAGE192(1);
  asm volatile("s_waitcnt vmcnt(7)" ::: "memory");
  BAR();

  short8 af[4][2];
  short8 bf[3][2];

  for (int t = 0; t < NT; ++t) {
    const char* ab = (const char*)&LA[t & 1][0];
    const char* bb = (const char*)&LB[t & 1][0];

    // P0: A(M-half0) + B(n0,n1); MFMA m0-3 x n0-1
#pragma unroll
    for (int m = 0; m < 4; ++m)
#pragma unroll
      for (int kk = 0; kk < 2; ++kk)
        af[m][kk] = *(const short8*)(ab + (wm * 128 + m * 16 + l15) * 128 +
                                     ((kk * 64 + lg * 16) ^ xr));
#pragma unroll
    for (int n = 0; n < 2; ++n)
#pragma unroll
      for (int kk = 0; kk < 2; ++kk)
        bf[n][kk] = *(const short8*)(bb + (wn * 48 + n * 16 + l15) * 128 +
                                     ((kk * 64 + lg * 16) ^ xr));
    BAR();
    __builtin_amdgcn_s_setprio(1);
#pragma unroll
    for (int m = 0; m < 4; ++m)
#pragma unroll
      for (int n = 0; n < 2; ++n)
#pragma unroll
        for (int kk = 0; kk < 2; ++kk)
          acc[m][n] = __builtin_amdgcn_mfma_f32_16x16x32_bf16(
              af[m][kk], bf[n][kk], acc[m][n], 0, 0, 0);
    __builtin_amdgcn_s_setprio(0);
    BAR();

    // P1: B(n2); MFMA m0-3 x n2
#pragma unroll
    for (int kk = 0; kk < 2; ++kk)
      bf[2][kk] = *(const short8*)(bb + (wn * 48 + 32 + l15) * 128 +
                                   ((kk * 64 + lg * 16) ^ xr));
    BAR();
    __builtin_amdgcn_s_setprio(1);
#pragma unroll
    for (int m = 0; m < 4; ++m)
#pragma unroll
      for (int kk = 0; kk < 2; ++kk)
        acc[m][2] = __builtin_amdgcn_mfma_f32_16x16x32_bf16(
            af[m][kk], bf[2][kk], acc[m][2], 0, 0, 0);
    __builtin_amdgcn_s_setprio(0);
    BAR();

    // P2: A(M-half1); MFMA m4-7 x n2
#pragma unroll
    for (int m = 0; m < 4; ++m)
#pragma unroll
      for (int kk = 0; kk < 2; ++kk)
        af[m][kk] = *(const short8*)(ab + (wm * 128 + 64 + m * 16 + l15) * 128 +
                                     ((kk * 64 + lg * 16) ^ xr));
    BAR();
    __builtin_amdgcn_s_setprio(1);
#pragma unroll
    for (int m = 0; m < 4; ++m)
#pragma unroll
      for (int kk = 0; kk < 2; ++kk)
        acc[4 + m][2] = __builtin_amdgcn_mfma_f32_16x16x32_bf16(
            af[m][kk], bf[2][kk], acc[4 + m][2], 0, 0, 0);
    __builtin_amdgcn_s_setprio(0);
    BAR();

    // P3: stage t+2; MFMA m4-7 x n0-1; counted vmcnt(7)
    if (t + 2 < NT) STAGE192(t + 2);
    __builtin_amdgcn_s_setprio(1);
#pragma unroll
    for (int m = 0; m < 4; ++m)
#pragma unroll
      for (int n = 0; n < 2; ++n)
#pragma unroll
        for (int kk = 0; kk < 2; ++kk)
          acc[4 + m][n] = __builtin_amdgcn_mfma_f32_16x16x32_bf16(
              af[m][kk], bf[n][kk], acc[4 + m][n], 0, 0, 0);
    __builtin_amdgcn_s_setprio(0);
    if (t + 2 < NT) {
      asm volatile("s_waitcnt vmcnt(7)" ::: "memory");
    } else if (t + 1 < NT) {
      asm volatile("s_waitcnt vmcnt(0)" ::: "memory");
    }
    BAR();
  }

#pragma unroll
  for (int m = 0; m < 8; ++m)
#pragma unroll
    for (int n = 0; n < 3; ++n)
#pragma unroll
      for (int r = 0; r < 4; ++r)
        C[(size_t)(row0 + wm * 128 + m * 16 + lg * 4 + r) * N + col0 +
          wn * 48 + n * 16 + l15] = acc[m][n][r];
#undef STAGE192
}

// ---------------------------------------------------------------------------
// fp32 -> bf16 flat convert
// ---------------------------------------------------------------------------
__global__ __launch_bounds__(256) void conv_bf16(const float* __restrict__ s,
                                                 u16* __restrict__ d, int n) {
  const int i = (blockIdx.x * 256 + threadIdx.x) * 8;
  if (i >= n) return;
  const float4 a = *(const float4*)(s + i);
  const float4 b = *(const float4*)(s + i + 4);
  u32x4 pk;
  pk[0] = pack2(a.x, a.y); pk[1] = pack2(a.z, a.w);
  pk[2] = pack2(b.x, b.y); pk[3] = pack2(b.z, b.w);
  *(u32x4*)(d + i) = pk;
}

// fp32 [R][Cn] -> bf16 [Cn][R] transpose
__global__ __launch_bounds__(256) void transpose_bf16(const float* __restrict__ s,
                                                      u16* __restrict__ d,
                                                      int R, int Cn) {
  __shared__ float t[32][33];
  const int tx = threadIdx.x & 31;
  const int ty = threadIdx.x >> 5;
  const int x = blockIdx.x * 32 + tx;
#pragma unroll
  for (int j = 0; j < 4; ++j)
    t[ty + j * 8][tx] = s[(size_t)(blockIdx.y * 32 + ty + j * 8) * Cn + x];
  __syncthreads();
  const int xo = blockIdx.y * 32 + tx;
#pragma unroll
  for (int j = 0; j < 4; ++j)
    d[(size_t)(blockIdx.x * 32 + ty + j * 8) * R + xo] = f2bf(t[tx][ty + j * 8]);
}

// kv [B*S][256] fp32 cols 128..255  ->  vt [B][128][S] bf16 (V transposed)
__global__ __launch_bounds__(256) void transpose_v(const float* __restrict__ kv,
                                                   u16* __restrict__ vt) {
  __shared__ float t[32][33];
  const int tx = threadIdx.x & 31;
  const int ty = threadIdx.x >> 5;
  const int st = blockIdx.x;
  const int dt = blockIdx.y;
  const int b = blockIdx.z;
#pragma unroll
  for (int j = 0; j < 4; ++j)
    t[ty + j * 8][tx] =
        kv[(size_t)(b * S_SZ + st * 32 + ty + j * 8) * 256 + 128 + dt * 32 + tx];
  __syncthreads();
#pragma unroll
  for (int j = 0; j < 4; ++j)
    vt[(size_t)(b * D_SZ + dt * 32 + ty + j * 8) * S_SZ + st * 32 + tx] =
        f2bf(t[tx][ty + j * 8]);
}

// ---------------------------------------------------------------------------
// fp32 LayerNorm (D=128) + interleaved RoPE, bf16 out (k path only).
// ---------------------------------------------------------------------------
__global__ __launch_bounds__(128) void ln_rope(const float* __restrict__ X,
                                               int xstride, u16* __restrict__ Y,
                                               const float* __restrict__ g,
                                               const float* __restrict__ be,
                                               const float* __restrict__ fc,
                                               const float* __restrict__ fs,
                                               int heads, float oscale) {
  __shared__ float red[4];
  const int row = blockIdx.x;
  const int d = threadIdx.x;
  const int s = (row / heads) % S_SZ;

  const float x = X[(size_t)row * xstride + d];
  float v1 = x, v2 = x * x;
#pragma unroll
  for (int off = 1; off < 64; off <<= 1) {
    v1 += __shfl_xor(v1, off);
    v2 += __shfl_xor(v2, off);
  }
  if ((d & 63) == 0) { red[(d >> 6) * 2] = v1; red[(d >> 6) * 2 + 1] = v2; }
  __syncthreads();
  const float mean = (red[0] + red[2]) * (1.f / 128.f);
  const float var = (red[1] + red[3]) * (1.f / 128.f) - mean * mean;
  const float inv = rsqrtf(var + EPS_LN);
  const float y = (x - mean) * inv * g[d] + be[d];
  const float yp = __shfl_xor(y, 1);
  const float c = fc[(size_t)s * D_SZ + d];
  const float sn = fs[(size_t)s * D_SZ + d];
  const float o = (d & 1) ? (yp * sn + y * c) : (y * c - yp * sn);
  Y[(size_t)row * D_SZ + d] = f2bf(o * oscale);
}

// ---------------------------------------------------------------------------
// Flash MQA attention with fused Q LayerNorm+RoPE (round-17 validated order:
// Q prologue first, then tile-0 staging — the reordered variant raced).
// ---------------------------------------------------------------------------
__global__ __launch_bounds__(256, 3) void attn_mfma32(
    const float* __restrict__ Qf, const u16* __restrict__ Kbf,
    const u16* __restrict__ Vt, const float* __restrict__ lnw,
    const float* __restrict__ lnb, const float* __restrict__ fcos,
    const float* __restrict__ fsin, u16* __restrict__ Obf) {
  __shared__ char LB[2][16384];

  const int tid = threadIdx.x;
  const int l = tid & 63;
  const int w = tid >> 6;
  const int l31 = l & 31;
  const int hh = l >> 5;

  const int bid = blockIdx.x;
  const int qt = bid & 15;
  const int h = (bid >> 4) % H_SZ;
  const int b = bid / (16 * H_SZ);

  // ---- fused LN+RoPE Q load: fp32 projection -> bf16 fragments ----
  short8 qf[8];
  {
    const int si = qt * 128 + w * 32 + l31;
    const float* qp =
        Qf + (size_t)(b * S_SZ + si) * (H_SZ * D_SZ) + h * D_SZ + hh * 8;
    float qv[64];
#pragma unroll
    for (int dk = 0; dk < 8; ++dk) {
      *(float4*)&qv[dk * 8] = *(const float4*)(qp + dk * 16);
      *(float4*)&qv[dk * 8 + 4] = *(const float4*)(qp + dk * 16 + 4);
    }
    float s1 = 0.f, s2 = 0.f;
#pragma unroll
    for (int i = 0; i < 64; ++i) { s1 += qv[i]; s2 += qv[i] * qv[i]; }
    s1 += __shfl_xor(s1, 32);
    s2 += __shfl_xor(s2, 32);
    const float mean = s1 * (1.f / 128.f);
    const float var = s2 * (1.f / 128.f) - mean * mean;
    const float inv = rsqrtf(var + EPS_LN);
    const float sc = 0.12751743559f;  // log2(e)/sqrt(128)
    const float* fcp = fcos + (size_t)si * D_SZ + hh * 8;
    const float* fsp = fsin + (size_t)si * D_SZ + hh * 8;
    const float* gp = lnw + hh * 8;
    const float* bp = lnb + hh * 8;
#pragma unroll
    for (int dk = 0; dk < 8; ++dk) {
      u32x4 pw;
#pragma unroll
      for (int j = 0; j < 4; ++j) {
        const int e = dk * 16 + 2 * j;  // element offset rel. to hh*8 base
        const float y0 = (qv[dk * 8 + 2 * j] - mean) * inv * gp[e] + bp[e];
        const float y1 =
            (qv[dk * 8 + 2 * j + 1] - mean) * inv * gp[e + 1] + bp[e + 1];
        const float c = fcp[e];
        const float sn = fsp[e];
        pw[j] = cvtpk((y0 * c - y1 * sn) * sc, (y0 * sn + y1 * c) * sc);
      }
      qf[dk] = *(const short8*)&pw;
    }
  }

  const char* kSrc[2];
  const char* vSrc[2];
  int kLds[2], vLds[2];
#pragma unroll
  for (int i = 0; i < 2; ++i) {
    const int o = (tid + i * 256) * 16;
    {
      const int r = o >> 8;
      const int cl = (o & 255) ^ ((r & 7) << 4) ^ (((r >> 3) & 1) << 7);
      kSrc[i] = (const char*)Kbf + (size_t)(b * S_SZ + r) * 256 + cl;
      kLds[i] = o;
    }
    {
      const int r = o >> 7;
      const int cl = (o & 127) ^ ((r & 7) << 4);
      const int d = r + ((cl >> 6) << 6);
      vSrc[i] = (const char*)Vt + (size_t)(b * D_SZ + d) * (S_SZ * 2) + (cl & 63);
      vLds[i] = 8192 + o;
    }
  }

  f32x16 oa[4];
#pragma unroll
  for (int db = 0; db < 4; ++db) oa[db] = (f32x16)0.f;
  float m_run = -1e30f, l_run = 0.f;

  const int swzK = ((l31 & 7) << 4) ^ (((l31 >> 3) & 1) << 7);

#pragma unroll
  for (int i = 0; i < 2; ++i) {
    gload_lds16(kSrc[i], &LB[0][kLds[i]]);
    gload_lds16(vSrc[i], &LB[0][vLds[i]]);
  }

  for (int t = 0; t < S_SZ / 32; ++t) {
    __syncthreads();
    if (t < S_SZ / 32 - 1) {
      const int nb = (t + 1) & 1;
#pragma unroll
      for (int i = 0; i < 2; ++i) {
        gload_lds16(kSrc[i] + (size_t)(t + 1) * 8192, &LB[nb][kLds[i]]);
        gload_lds16(vSrc[i] + (t + 1) * 64, &LB[nb][vLds[i]]);
      }
    }
    const char* Kb = &LB[t & 1][0];
    const char* Vb = &LB[t & 1][8192];

    f32x16 s0 = (f32x16)0.f;
    __builtin_amdgcn_s_setprio(1);
#pragma unroll
    for (int dk = 0; dk < 8; ++dk) {
      const short8 a0 = *(const short8*)(Kb + l31 * 256 + ((dk * 32 + hh * 16) ^ swzK));
      s0 = __builtin_amdgcn_mfma_f32_32x32x16_bf16(a0, qf[dk], s0, 0, 0, 0);
    }
    __builtin_amdgcn_s_setprio(0);

    const float t0 = fmaxf(fmaxf(s0[0], s0[1]), s0[2]);
    const float t1 = fmaxf(fmaxf(s0[3], s0[4]), s0[5]);
    const float t2 = fmaxf(fmaxf(s0[6], s0[7]), s0[8]);
    const float t3 = fmaxf(fmaxf(s0[9], s0[10]), s0[11]);
    const float t4 = fmaxf(fmaxf(s0[12], s0[13]), s0[14]);
    float pm = fmaxf(fmaxf(fmaxf(t0, t1), t2), fmaxf(fmaxf(t3, t4), s0[15]));
    pm = fmaxf(pm, __shfl_xor(pm, 32));
    if (!__all(pm <= m_run + 11.5416f)) {
      const float mnew = fmaxf(m_run, pm);
      const float corr = fexp2(m_run - mnew);
      m_run = mnew;
      l_run *= corr;
#pragma unroll
      for (int r = 0; r < 16; ++r) {
        const float cq = __shfl(corr, (r & 3) + 8 * (r >> 2) + 4 * hh);
#pragma unroll
        for (int db = 0; db < 4; ++db) oa[db][r] *= cq;
      }
    }
#pragma unroll
    for (int r = 0; r < 16; ++r) s0[r] = fexp2(s0[r] - m_run);
    const float p0 = (s0[0] + s0[1]) + (s0[2] + s0[3]);
    const float p1 = (s0[4] + s0[5]) + (s0[6] + s0[7]);
    const float p2 = (s0[8] + s0[9]) + (s0[10] + s0[11]);
    const float p3 = (s0[12] + s0[13]) + (s0[14] + s0[15]);
    l_run += (p0 + p1) + (p2 + p3);  // per-lane partial; combine at epilogue

#pragma unroll
    for (int ks = 0; ks < 2; ++ks) {
      const int rA = ks * 8;
      const int rB = ks * 8 + 4;
      const unsigned xA0 = cvtpk(s0[rA + 0], s0[rA + 1]);
      const unsigned xA1 = cvtpk(s0[rA + 2], s0[rA + 3]);
      const unsigned xB0 = cvtpk(s0[rB + 0], s0[rB + 1]);
      const unsigned xB1 = cvtpk(s0[rB + 2], s0[rB + 3]);
      const unsigned pA0 = (unsigned)__shfl_xor((int)xA0, 32);
      const unsigned pA1 = (unsigned)__shfl_xor((int)xA1, 32);
      const unsigned pB0 = (unsigned)__shfl_xor((int)xB0, 32);
      const unsigned pB1 = (unsigned)__shfl_xor((int)xB1, 32);
      u32x4 paw;
      paw[0] = hh ? pB0 : xA0;
      paw[1] = hh ? pB1 : xA1;
      paw[2] = hh ? xB0 : pA0;
      paw[3] = hh ? xB1 : pA1;
      const short8 pa = *(const short8*)&paw;
      __builtin_amdgcn_s_setprio(1);
#pragma unroll
      for (int db = 0; db < 4; ++db) {
        const int d = db * 32 + l31;
        const int r = d & 63;
        const int cl = ks * 32 + hh * 16 + ((d >> 6) << 6);
        const short8 vb = *(const short8*)(Vb + r * 128 + (cl ^ ((r & 7) << 4)));
        oa[db] = __builtin_amdgcn_mfma_f32_32x32x16_bf16(pa, vb, oa[db], 0, 0, 0);
      }
      __builtin_amdgcn_s_setprio(0);
    }
  }

  l_run += __shfl_xor(l_run, 32);  // deferred cross-half combine
  const float linv = 1.f / l_run;
#pragma unroll
  for (int r = 0; r < 16; ++r) {
    const int crow = (r & 3) + 8 * (r >> 2) + 4 * hh;
    const float inv = __shfl(linv, crow);
    u16* op = Obf + (size_t)(b * S_SZ + qt * 128 + w * 32 + crow) * (H_SZ * D_SZ) +
              h * D_SZ + l31;
#pragma unroll
    for (int db = 0; db < 4; ++db) op[db * 32] = f2bf(oa[db][r] * inv);
  }
}

// ---------------------------------------------------------------------------
extern "C" void kernel_launch(void* const* d_in, const int* in_sizes, int n_in,
                              void* d_out, int out_size, void* d_ws,
                              size_t ws_size, hipStream_t stream) {
  const float* hidden = (const float*)d_in[0];
  const float* fcos = (const float*)d_in[1];
  const float* fsin = (const float*)d_in[2];
  const float* w_q = (const float*)d_in[3];
  const float* w_k = (const float*)d_in[4];
  const float* w_v = (const float*)d_in[5];
  const float* w_o = (const float*)d_in[6];
  const float* ln_q_w = (const float*)d_in[7];
  const float* ln_q_b = (const float*)d_in[8];
  const float* ln_k_w = (const float*)d_in[9];
  const float* ln_k_b = (const float*)d_in[10];
  float* out = (float*)d_out;

  const int M = B_SZ * S_SZ;  // 4096

  char* ws = (char*)d_ws;
  u16* hid_bf = (u16*)ws;                       // 25165824 B [aliased a_bf]
  u16* wqt = (u16*)(ws + 25165824);             // 18874368 B [reused: w_o^T]
  u16* wkvt = (u16*)(ws + 44040192);            //  1572864 B (contiguous w/ wqt)
  float* kv_buf = (float*)(ws + 45613056);      //  4194304 B
  u16* k_bf = (u16*)(ws + 49807360);            //  1048576 B
  u16* vt_bf = (u16*)(ws + 50855936);           //  1048576 B (V^T [B][128][S])
  u16* a_bf = hid_bf;   // attn out reuses hid_bf (dead after qkv GEMM)
  float* q_f32 = out;   // fp32 q projection lives in d_out until attn

  conv_bf16<<<(M * DIM_SZ) / 2048, 256, 0, stream>>>(hidden, hid_bf, M * DIM_SZ);
  transpose_bf16<<<dim3(DIM_SZ / 32, DIM_SZ / 32), 256, 0, stream>>>(
      w_q, wqt, DIM_SZ, DIM_SZ);
  transpose_bf16<<<dim3(D_SZ / 32, DIM_SZ / 32), 256, 0, stream>>>(
      w_k, wkvt, DIM_SZ, D_SZ);
  transpose_bf16<<<dim3(D_SZ / 32, DIM_SZ / 32), 256, 0, stream>>>(
      w_v, wkvt + (size_t)D_SZ * DIM_SZ, DIM_SZ, D_SZ);

  // fused q+kv projection: Bt = [w_q^T | w_k^T | w_v^T], N=3328;
  // cols < 3072 -> q_f32, cols >= 3072 -> kv_buf.  grid 16x13=208 (%8==0).
  gemm256<<<(M / 256) * (3328 / 256), 512, 0, stream>>>(
      hid_bf, wqt, q_f32, kv_buf, M, 3328, DIM_SZ, DIM_SZ);
  transpose_bf16<<<dim3(DIM_SZ / 32, DIM_SZ / 32), 256, 0, stream>>>(
      w_o, wqt, DIM_SZ, DIM_SZ);

  // k-path LN+RoPE (q-path is fused into the attention kernel)
  ln_rope<<<M, 128, 0, stream>>>(kv_buf, 256, k_bf, ln_k_w, ln_k_b, fcos, fsin,
                                 1, 1.0f);
  transpose_v<<<dim3(S_SZ / 32, D_SZ / 32, B_SZ), 256, 0, stream>>>(kv_buf,
                                                                    vt_bf);

  attn_mfma32<<<B_SZ * H_SZ * 16, 256, 0, stream>>>(
      q_f32, k_bf, vt_bf, ln_q_w, ln_q_b, fcos, fsin, a_bf);

  // output projection: 256x192 tiles -> grid 16x16 = 256 blocks.
  gemm192<<<(M / 256) * (DIM_SZ / 192), 512, 0, stream>>>(a_bf, wqt, out, M,
                                                          DIM_SZ, DIM_SZ);
}

// Round 20
// 346.293 us; speedup vs baseline: 1.0074x; 1.0074x over previous
//
#include <hip/hip_runtime.h>
#include <hip/hip_bf16.h>

#define B_SZ 2
#define S_SZ 2048
#define DIM_SZ 3072
#define H_SZ 24
#define D_SZ 128
#define EPS_LN 1e-6f

typedef __attribute__((ext_vector_type(8))) short short8;
typedef __attribute__((ext_vector_type(4))) float f32x4;
typedef __attribute__((ext_vector_type(16))) float f32x16;
typedef __attribute__((ext_vector_type(4))) unsigned int u32x4;
typedef unsigned short u16;

__device__ __forceinline__ float fexp2(float x) {
  return __builtin_amdgcn_exp2f(x);  // v_exp_f32 (native base-2)
}

__device__ __forceinline__ u16 f2bf(float f) {
  union { float f; unsigned u; } x; x.f = f;
  unsigned r = x.u + 0x7fffu + ((x.u >> 16) & 1u);  // RNE
  return (u16)(r >> 16);
}
__device__ __forceinline__ unsigned pack2(float a, float b) {
  return (unsigned)f2bf(a) | ((unsigned)f2bf(b) << 16);
}
__device__ __forceinline__ unsigned cvtpk(float a, float b) {
  unsigned r;
  asm("v_cvt_pk_bf16_f32 %0, %1, %2" : "=v"(r) : "v"(a), "v"(b));
  return r;
}

// async global->LDS, 16B per lane (wave-uniform LDS base + lane*16).
typedef const __attribute__((address_space(1))) void* gas_ptr;
typedef __attribute__((address_space(3))) void* las_ptr;
__device__ __forceinline__ void gload_lds16(const void* g, void* l) {
  __builtin_amdgcn_global_load_lds(
      reinterpret_cast<gas_ptr>(reinterpret_cast<uintptr_t>(g)),
      reinterpret_cast<las_ptr>(reinterpret_cast<uintptr_t>(l)), 16, 0, 0);
}

#define BAR()                              \
  {                                        \
    __builtin_amdgcn_sched_barrier(0);     \
    __builtin_amdgcn_s_barrier();          \
    __builtin_amdgcn_sched_barrier(0);     \
  }

// ---------------------------------------------------------------------------
// 256x256 deep-pipelined bf16 MFMA GEMM (twice-verified config: fp32 split
// C-write).  8 waves (2Mx4N), per-wave 128x64, BK=64, LDS 128KB, counted
// vmcnt(8).  cols < Nsplit -> C, else -> C2 (block-uniform).  Stage of tile
// t+2 happens entirely at P3 (race-free proven config).
// ---------------------------------------------------------------------------
__global__ __launch_bounds__(512, 2) void gemm256(const u16* __restrict__ A,
                                                  const u16* __restrict__ Bt,
                                                  float* __restrict__ C,
                                                  float* __restrict__ C2,
                                                  int M, int N, int Nsplit,
                                                  int K) {
  __shared__ u16 LDSb[2][2][256 * 64];  // [buf][A/B][row*64+k]  128 KB

  const int tid = threadIdx.x;
  const int l15 = tid & 15;
  const int lg = (tid >> 4) & 3;
  const int wv = tid >> 6;   // 0..7
  const int wm = wv >> 2;    // 0..1  (M half)
  const int wn = wv & 3;     // 0..3  (N quarter)

  const int nbx = N >> 8;
  int bid = (int)blockIdx.x;
  const int cpx = (int)gridDim.x >> 3;  // grid % 8 == 0 (bijective XCD swizzle)
  bid = (bid & 7) * cpx + (bid >> 3);
  const int row0 = (bid / nbx) * 256;
  const int col0 = (bid % nbx) * 256;

  size_t asrc[4], bsrc[4];
  int loff[4];
#pragma unroll
  for (int j = 0; j < 4; ++j) {
    const int o = (tid + j * 512) * 16;         // [0, 32768)
    const int r = o >> 7;                       // LDS row 0..255
    const int sb = (o & 127) ^ ((r & 7) << 4);  // swizzled byte-in-row
    loff[j] = o;
    asrc[j] = (size_t)(row0 + r) * K + (sb >> 1);
    bsrc[j] = (size_t)(col0 + r) * K + (sb >> 1);
  }
  const int xr = (l15 & 7) << 4;

  f32x4 acc[8][4];
#pragma unroll
  for (int m = 0; m < 8; ++m)
#pragma unroll
    for (int n = 0; n < 4; ++n) acc[m][n] = (f32x4)0.f;

  const int NT = K >> 6;

#define STAGE256(t)                                                         \
  {                                                                         \
    char* abL = (char*)&LDSb[(t) & 1][0][0];                                \
    char* bbL = (char*)&LDSb[(t) & 1][1][0];                                \
    _Pragma("unroll") for (int j = 0; j < 4; ++j)                           \
        gload_lds16(A + asrc[j] + (size_t)(t) * 64, abL + loff[j]);         \
    _Pragma("unroll") for (int j = 0; j < 4; ++j)                           \
        gload_lds16(Bt + bsrc[j] + (size_t)(t) * 64, bbL + loff[j]);        \
  }

  STAGE256(0);
  STAGE256(1);
  asm volatile("s_waitcnt vmcnt(8)" ::: "memory");
  BAR();

  short8 af[4][2];
  short8 bf[4][2];

  for (int t = 0; t < NT; ++t) {
    const char* ab = (const char*)&LDSb[t & 1][0][0];
    const char* bb = (const char*)&LDSb[t & 1][1][0];

    // P0: A(M-half0) + B(n0,n1); MFMA Q0
#pragma unroll
    for (int m = 0; m < 4; ++m)
#pragma unroll
      for (int kk = 0; kk < 2; ++kk)
        af[m][kk] = *(const short8*)(ab + (wm * 128 + m * 16 + l15) * 128 +
                                     ((kk * 64 + lg * 16) ^ xr));
#pragma unroll
    for (int n = 0; n < 2; ++n)
#pragma unroll
      for (int kk = 0; kk < 2; ++kk)
        bf[n][kk] = *(const short8*)(bb + (wn * 64 + n * 16 + l15) * 128 +
                                     ((kk * 64 + lg * 16) ^ xr));
    BAR();
    __builtin_amdgcn_s_setprio(1);
#pragma unroll
    for (int m = 0; m < 4; ++m)
#pragma unroll
      for (int n = 0; n < 2; ++n)
#pragma unroll
        for (int kk = 0; kk < 2; ++kk)
          acc[m][n] = __builtin_amdgcn_mfma_f32_16x16x32_bf16(
              af[m][kk], bf[n][kk], acc[m][n], 0, 0, 0);
    __builtin_amdgcn_s_setprio(0);
    BAR();

    // P1: B(n2,n3); MFMA Q1
#pragma unroll
    for (int n = 2; n < 4; ++n)
#pragma unroll
      for (int kk = 0; kk < 2; ++kk)
        bf[n][kk] = *(const short8*)(bb + (wn * 64 + n * 16 + l15) * 128 +
                                     ((kk * 64 + lg * 16) ^ xr));
    BAR();
    __builtin_amdgcn_s_setprio(1);
#pragma unroll
    for (int m = 0; m < 4; ++m)
#pragma unroll
      for (int n = 2; n < 4; ++n)
#pragma unroll
        for (int kk = 0; kk < 2; ++kk)
          acc[m][n] = __builtin_amdgcn_mfma_f32_16x16x32_bf16(
              af[m][kk], bf[n][kk], acc[m][n], 0, 0, 0);
    __builtin_amdgcn_s_setprio(0);
    BAR();

    // P2: A(M-half1); MFMA Q2
#pragma unroll
    for (int m = 0; m < 4; ++m)
#pragma unroll
      for (int kk = 0; kk < 2; ++kk)
        af[m][kk] = *(const short8*)(ab + (wm * 128 + 64 + m * 16 + l15) * 128 +
                                     ((kk * 64 + lg * 16) ^ xr));
    BAR();
    __builtin_amdgcn_s_setprio(1);
#pragma unroll
    for (int m = 0; m < 4; ++m)
#pragma unroll
      for (int n = 2; n < 4; ++n)
#pragma unroll
        for (int kk = 0; kk < 2; ++kk)
          acc[4 + m][n] = __builtin_amdgcn_mfma_f32_16x16x32_bf16(
              af[m][kk], bf[n][kk], acc[4 + m][n], 0, 0, 0);
    __builtin_amdgcn_s_setprio(0);
    BAR();

    // P3: stage t+2; MFMA Q3; counted vmcnt
    if (t + 2 < NT) STAGE256(t + 2);
    __builtin_amdgcn_s_setprio(1);
#pragma unroll
    for (int m = 0; m < 4; ++m)
#pragma unroll
      for (int n = 0; n < 2; ++n)
#pragma unroll
        for (int kk = 0; kk < 2; ++kk)
          acc[4 + m][n] = __builtin_amdgcn_mfma_f32_16x16x32_bf16(
              af[m][kk], bf[n][kk], acc[4 + m][n], 0, 0, 0);
    __builtin_amdgcn_s_setprio(0);
    if (t + 2 < NT) {
      asm volatile("s_waitcnt vmcnt(8)" ::: "memory");
    } else if (t + 1 < NT) {
      asm volatile("s_waitcnt vmcnt(0)" ::: "memory");
    }
    BAR();
  }

  const bool lo = (col0 < Nsplit);
  float* Cw = lo ? C : C2;
  const int cw = lo ? Nsplit : (N - Nsplit);
  const int cb = col0 - (lo ? 0 : Nsplit);
#pragma unroll
  for (int m = 0; m < 8; ++m)
#pragma unroll
    for (int n = 0; n < 4; ++n)
#pragma unroll
      for (int r = 0; r < 4; ++r)
        Cw[(size_t)(row0 + wm * 128 + m * 16 + lg * 4 + r) * cw + cb +
           wn * 64 + n * 16 + l15] = acc[m][n][r];
#undef STAGE256
}

// ---------------------------------------------------------------------------
// 256x192-tile 4-phase pipeline for N=3072 outputs (validated round-12):
// grid 16x16 = 256 blocks -> 100% CU coverage.  vmcnt(7) = 4A+3B loads/tile.
// ---------------------------------------------------------------------------
__global__ __launch_bounds__(512, 2) void gemm192(const u16* __restrict__ A,
                                                  const u16* __restrict__ Bt,
                                                  float* __restrict__ C,
                                                  int M, int N, int K) {
  __shared__ u16 LA[2][256 * 64];  // 64 KB
  __shared__ u16 LB[2][192 * 64];  // 48 KB

  const int tid = threadIdx.x;
  const int l15 = tid & 15;
  const int lg = (tid >> 4) & 3;
  const int wv = tid >> 6;
  const int wm = wv >> 2;   // 0..1
  const int wn = wv & 3;    // 0..3 -> 48-col strip

  const int nbx = N / 192;
  int bid = (int)blockIdx.x;
  const int cpx = (int)gridDim.x >> 3;
  bid = (bid & 7) * cpx + (bid >> 3);
  const int row0 = (bid / nbx) * 256;
  const int col0 = (bid % nbx) * 192;

  size_t asrc[4], bsrc[3];
  int aoff[4], boff[3];
#pragma unroll
  for (int j = 0; j < 4; ++j) {
    const int o = (tid + j * 512) * 16;  // [0, 32768)
    const int r = o >> 7;
    const int sb = (o & 127) ^ ((r & 7) << 4);
    aoff[j] = o;
    asrc[j] = (size_t)(row0 + r) * K + (sb >> 1);
  }
#pragma unroll
  for (int j = 0; j < 3; ++j) {
    const int o = (tid + j * 512) * 16;  // [0, 24576)
    const int r = o >> 7;                // 0..191
    const int sb = (o & 127) ^ ((r & 7) << 4);
    boff[j] = o;
    bsrc[j] = (size_t)(col0 + r) * K + (sb >> 1);
  }
  const int xr = (l15 & 7) << 4;

  f32x4 acc[8][3];
#pragma unroll
  for (int m = 0; m < 8; ++m)
#pragma unroll
    for (int n = 0; n < 3; ++n) acc[m][n] = (f32x4)0.f;

  const int NT = K >> 6;

#define STAGE192(t)                                                         \
  {                                                                         \
    char* abL = (char*)&LA[(t) & 1][0];                                     \
    char* bbL = (char*)&LB[(t) & 1][0];                                     \
    _Pragma("unroll") for (int j = 0; j < 4; ++j)                           \
        gload_lds16(A + asrc[j] + (size_t)(t) * 64, abL + aoff[j]);         \
    _Pragma("unroll") for (int j = 0; j < 3; ++j)                           \
        gload_lds16(Bt + bsrc[j] + (size_t)(t) * 64, bbL + boff[j]);        \
  }

  STAGE192(0);
  STAGE192(1);
  asm volatile("s_waitcnt vmcnt(7)" ::: "memory");
  BAR();

  short8 af[4][2];
  short8 bf[3][2];

  for (int t = 0; t < NT; ++t) {
    const char* ab = (const char*)&LA[t & 1][0];
    const char* bb = (const char*)&LB[t & 1][0];

    // P0: A(M-half0) + B(n0,n1); MFMA m0-3 x n0-1
#pragma unroll
    for (int m = 0; m < 4; ++m)
#pragma unroll
      for (int kk = 0; kk < 2; ++kk)
        af[m][kk] = *(const short8*)(ab + (wm * 128 + m * 16 + l15) * 128 +
                                     ((kk * 64 + lg * 16) ^ xr));
#pragma unroll
    for (int n = 0; n < 2; ++n)
#pragma unroll
      for (int kk = 0; kk < 2; ++kk)
        bf[n][kk] = *(const short8*)(bb + (wn * 48 + n * 16 + l15) * 128 +
                                     ((kk * 64 + lg * 16) ^ xr));
    BAR();
    __builtin_amdgcn_s_setprio(1);
#pragma unroll
    for (int m = 0; m < 4; ++m)
#pragma unroll
      for (int n = 0; n < 2; ++n)
#pragma unroll
        for (int kk = 0; kk < 2; ++kk)
          acc[m][n] = __builtin_amdgcn_mfma_f32_16x16x32_bf16(
              af[m][kk], bf[n][kk], acc[m][n], 0, 0, 0);
    __builtin_amdgcn_s_setprio(0);
    BAR();

    // P1: B(n2); MFMA m0-3 x n2
#pragma unroll
    for (int kk = 0; kk < 2; ++kk)
      bf[2][kk] = *(const short8*)(bb + (wn * 48 + 32 + l15) * 128 +
                                   ((kk * 64 + lg * 16) ^ xr));
    BAR();
    __builtin_amdgcn_s_setprio(1);
#pragma unroll
    for (int m = 0; m < 4; ++m)
#pragma unroll
      for (int kk = 0; kk < 2; ++kk)
        acc[m][2] = __builtin_amdgcn_mfma_f32_16x16x32_bf16(
            af[m][kk], bf[2][kk], acc[m][2], 0, 0, 0);
    __builtin_amdgcn_s_setprio(0);
    BAR();

    // P2: A(M-half1); MFMA m4-7 x n2
#pragma unroll
    for (int m = 0; m < 4; ++m)
#pragma unroll
      for (int kk = 0; kk < 2; ++kk)
        af[m][kk] = *(const short8*)(ab + (wm * 128 + 64 + m * 16 + l15) * 128 +
                                     ((kk * 64 + lg * 16) ^ xr));
    BAR();
    __builtin_amdgcn_s_setprio(1);
#pragma unroll
    for (int m = 0; m < 4; ++m)
#pragma unroll
      for (int kk = 0; kk < 2; ++kk)
        acc[4 + m][2] = __builtin_amdgcn_mfma_f32_16x16x32_bf16(
            af[m][kk], bf[2][kk], acc[4 + m][2], 0, 0, 0);
    __builtin_amdgcn_s_setprio(0);
    BAR();

    // P3: stage t+2; MFMA m4-7 x n0-1; counted vmcnt(7)
    if (t + 2 < NT) STAGE192(t + 2);
    __builtin_amdgcn_s_setprio(1);
#pragma unroll
    for (int m = 0; m < 4; ++m)
#pragma unroll
      for (int n = 0; n < 2; ++n)
#pragma unroll
        for (int kk = 0; kk < 2; ++kk)
          acc[4 + m][n] = __builtin_amdgcn_mfma_f32_16x16x32_bf16(
              af[m][kk], bf[n][kk], acc[4 + m][n], 0, 0, 0);
    __builtin_amdgcn_s_setprio(0);
    if (t + 2 < NT) {
      asm volatile("s_waitcnt vmcnt(7)" ::: "memory");
    } else if (t + 1 < NT) {
      asm volatile("s_waitcnt vmcnt(0)" ::: "memory");
    }
    BAR();
  }

#pragma unroll
  for (int m = 0; m < 8; ++m)
#pragma unroll
    for (int n = 0; n < 3; ++n)
#pragma unroll
      for (int r = 0; r < 4; ++r)
        C[(size_t)(row0 + wm * 128 + m * 16 + lg * 4 + r) * N + col0 +
          wn * 48 + n * 16 + l15] = acc[m][n][r];
#undef STAGE192
}

// ---------------------------------------------------------------------------
// fp32 -> bf16 flat convert
// ---------------------------------------------------------------------------
__global__ __launch_bounds__(256) void conv_bf16(const float* __restrict__ s,
                                                 u16* __restrict__ d, int n) {
  const int i = (blockIdx.x * 256 + threadIdx.x) * 8;
  if (i >= n) return;
  const float4 a = *(const float4*)(s + i);
  const float4 b = *(const float4*)(s + i + 4);
  u32x4 pk;
  pk[0] = pack2(a.x, a.y); pk[1] = pack2(a.z, a.w);
  pk[2] = pack2(b.x, b.y); pk[3] = pack2(b.z, b.w);
  *(u32x4*)(d + i) = pk;
}

// fp32 [R][Cn] -> bf16 [Cn][R] transpose
__global__ __launch_bounds__(256) void transpose_bf16(const float* __restrict__ s,
                                                      u16* __restrict__ d,
                                                      int R, int Cn) {
  __shared__ float t[32][33];
  const int tx = threadIdx.x & 31;
  const int ty = threadIdx.x >> 5;
  const int x = blockIdx.x * 32 + tx;
#pragma unroll
  for (int j = 0; j < 4; ++j)
    t[ty + j * 8][tx] = s[(size_t)(blockIdx.y * 32 + ty + j * 8) * Cn + x];
  __syncthreads();
  const int xo = blockIdx.y * 32 + tx;
#pragma unroll
  for (int j = 0; j < 4; ++j)
    d[(size_t)(blockIdx.x * 32 + ty + j * 8) * R + xo] = f2bf(t[tx][ty + j * 8]);
}

// kv [B*S][256] fp32 cols 128..255  ->  vt [B][128][S] bf16 (V transposed)
__global__ __launch_bounds__(256) void transpose_v(const float* __restrict__ kv,
                                                   u16* __restrict__ vt) {
  __shared__ float t[32][33];
  const int tx = threadIdx.x & 31;
  const int ty = threadIdx.x >> 5;
  const int st = blockIdx.x;
  const int dt = blockIdx.y;
  const int b = blockIdx.z;
#pragma unroll
  for (int j = 0; j < 4; ++j)
    t[ty + j * 8][tx] =
        kv[(size_t)(b * S_SZ + st * 32 + ty + j * 8) * 256 + 128 + dt * 32 + tx];
  __syncthreads();
#pragma unroll
  for (int j = 0; j < 4; ++j)
    vt[(size_t)(b * D_SZ + dt * 32 + ty + j * 8) * S_SZ + st * 32 + tx] =
        f2bf(t[tx][ty + j * 8]);
}

// ---------------------------------------------------------------------------
// fp32 LayerNorm (D=128) + interleaved RoPE, bf16 out (k path only).
// ---------------------------------------------------------------------------
__global__ __launch_bounds__(128) void ln_rope(const float* __restrict__ X,
                                               int xstride, u16* __restrict__ Y,
                                               const float* __restrict__ g,
                                               const float* __restrict__ be,
                                               const float* __restrict__ fc,
                                               const float* __restrict__ fs,
                                               int heads, float oscale) {
  __shared__ float red[4];
  const int row = blockIdx.x;
  const int d = threadIdx.x;
  const int s = (row / heads) % S_SZ;

  const float x = X[(size_t)row * xstride + d];
  float v1 = x, v2 = x * x;
#pragma unroll
  for (int off = 1; off < 64; off <<= 1) {
    v1 += __shfl_xor(v1, off);
    v2 += __shfl_xor(v2, off);
  }
  if ((d & 63) == 0) { red[(d >> 6) * 2] = v1; red[(d >> 6) * 2 + 1] = v2; }
  __syncthreads();
  const float mean = (red[0] + red[2]) * (1.f / 128.f);
  const float var = (red[1] + red[3]) * (1.f / 128.f) - mean * mean;
  const float inv = rsqrtf(var + EPS_LN);
  const float y = (x - mean) * inv * g[d] + be[d];
  const float yp = __shfl_xor(y, 1);
  const float c = fc[(size_t)s * D_SZ + d];
  const float sn = fs[(size_t)s * D_SZ + d];
  const float o = (d & 1) ? (yp * sn + y * c) : (y * c - yp * sn);
  Y[(size_t)row * D_SZ + d] = f2bf(o * oscale);
}

// ---------------------------------------------------------------------------
// Flash MQA attention with fused Q LayerNorm+RoPE (twice-verified order:
// Q prologue first, then tile-0 staging).
// ---------------------------------------------------------------------------
__global__ __launch_bounds__(256, 3) void attn_mfma32(
    const float* __restrict__ Qf, const u16* __restrict__ Kbf,
    const u16* __restrict__ Vt, const float* __restrict__ lnw,
    const float* __restrict__ lnb, const float* __restrict__ fcos,
    const float* __restrict__ fsin, u16* __restrict__ Obf) {
  __shared__ char LB[2][16384];

  const int tid = threadIdx.x;
  const int l = tid & 63;
  const int w = tid >> 6;
  const int l31 = l & 31;
  const int hh = l >> 5;

  const int bid = blockIdx.x;
  const int qt = bid & 15;
  const int h = (bid >> 4) % H_SZ;
  const int b = bid / (16 * H_SZ);

  // ---- fused LN+RoPE Q load: fp32 projection -> bf16 fragments ----
  short8 qf[8];
  {
    const int si = qt * 128 + w * 32 + l31;
    const float* qp =
        Qf + (size_t)(b * S_SZ + si) * (H_SZ * D_SZ) + h * D_SZ + hh * 8;
    float qv[64];
#pragma unroll
    for (int dk = 0; dk < 8; ++dk) {
      *(float4*)&qv[dk * 8] = *(const float4*)(qp + dk * 16);
      *(float4*)&qv[dk * 8 + 4] = *(const float4*)(qp + dk * 16 + 4);
    }
    float s1 = 0.f, s2 = 0.f;
#pragma unroll
    for (int i = 0; i < 64; ++i) { s1 += qv[i]; s2 += qv[i] * qv[i]; }
    s1 += __shfl_xor(s1, 32);
    s2 += __shfl_xor(s2, 32);
    const float mean = s1 * (1.f / 128.f);
    const float var = s2 * (1.f / 128.f) - mean * mean;
    const float inv = rsqrtf(var + EPS_LN);
    const float sc = 0.12751743559f;  // log2(e)/sqrt(128)
    const float* fcp = fcos + (size_t)si * D_SZ + hh * 8;
    const float* fsp = fsin + (size_t)si * D_SZ + hh * 8;
    const float* gp = lnw + hh * 8;
    const float* bp = lnb + hh * 8;
#pragma unroll
    for (int dk = 0; dk < 8; ++dk) {
      u32x4 pw;
#pragma unroll
      for (int j = 0; j < 4; ++j) {
        const int e = dk * 16 + 2 * j;  // element offset rel. to hh*8 base
        const float y0 = (qv[dk * 8 + 2 * j] - mean) * inv * gp[e] + bp[e];
        const float y1 =
            (qv[dk * 8 + 2 * j + 1] - mean) * inv * gp[e + 1] + bp[e + 1];
        const float c = fcp[e];
        const float sn = fsp[e];
        pw[j] = cvtpk((y0 * c - y1 * sn) * sc, (y0 * sn + y1 * c) * sc);
      }
      qf[dk] = *(const short8*)&pw;
    }
  }

  const char* kSrc[2];
  const char* vSrc[2];
  int kLds[2], vLds[2];
#pragma unroll
  for (int i = 0; i < 2; ++i) {
    const int o = (tid + i * 256) * 16;
    {
      const int r = o >> 8;
      const int cl = (o & 255) ^ ((r & 7) << 4) ^ (((r >> 3) & 1) << 7);
      kSrc[i] = (const char*)Kbf + (size_t)(b * S_SZ + r) * 256 + cl;
      kLds[i] = o;
    }
    {
      const int r = o >> 7;
      const int cl = (o & 127) ^ ((r & 7) << 4);
      const int d = r + ((cl >> 6) << 6);
      vSrc[i] = (const char*)Vt + (size_t)(b * D_SZ + d) * (S_SZ * 2) + (cl & 63);
      vLds[i] = 8192 + o;
    }
  }

  f32x16 oa[4];
#pragma unroll
  for (int db = 0; db < 4; ++db) oa[db] = (f32x16)0.f;
  float m_run = -1e30f, l_run = 0.f;

  const int swzK = ((l31 & 7) << 4) ^ (((l31 >> 3) & 1) << 7);

#pragma unroll
  for (int i = 0; i < 2; ++i) {
    gload_lds16(kSrc[i], &LB[0][kLds[i]]);
    gload_lds16(vSrc[i], &LB[0][vLds[i]]);
  }

  for (int t = 0; t < S_SZ / 32; ++t) {
    __syncthreads();
    if (t < S_SZ / 32 - 1) {
      const int nb = (t + 1) & 1;
#pragma unroll
      for (int i = 0; i < 2; ++i) {
        gload_lds16(kSrc[i] + (size_t)(t + 1) * 8192, &LB[nb][kLds[i]]);
        gload_lds16(vSrc[i] + (t + 1) * 64, &LB[nb][vLds[i]]);
      }
    }
    const char* Kb = &LB[t & 1][0];
    const char* Vb = &LB[t & 1][8192];

    f32x16 s0 = (f32x16)0.f;
    __builtin_amdgcn_s_setprio(1);
#pragma unroll
    for (int dk = 0; dk < 8; ++dk) {
      const short8 a0 = *(const short8*)(Kb + l31 * 256 + ((dk * 32 + hh * 16) ^ swzK));
      s0 = __builtin_amdgcn_mfma_f32_32x32x16_bf16(a0, qf[dk], s0, 0, 0, 0);
    }
    __builtin_amdgcn_s_setprio(0);

    const float t0 = fmaxf(fmaxf(s0[0], s0[1]), s0[2]);
    const float t1 = fmaxf(fmaxf(s0[3], s0[4]), s0[5]);
    const float t2 = fmaxf(fmaxf(s0[6], s0[7]), s0[8]);
    const float t3 = fmaxf(fmaxf(s0[9], s0[10]), s0[11]);
    const float t4 = fmaxf(fmaxf(s0[12], s0[13]), s0[14]);
    float pm = fmaxf(fmaxf(fmaxf(t0, t1), t2), fmaxf(fmaxf(t3, t4), s0[15]));
    pm = fmaxf(pm, __shfl_xor(pm, 32));
    if (!__all(pm <= m_run + 11.5416f)) {
      const float mnew = fmaxf(m_run, pm);
      const float corr = fexp2(m_run - mnew);
      m_run = mnew;
      l_run *= corr;
#pragma unroll
      for (int r = 0; r < 16; ++r) {
        const float cq = __shfl(corr, (r & 3) + 8 * (r >> 2) + 4 * hh);
#pragma unroll
        for (int db = 0; db < 4; ++db) oa[db][r] *= cq;
      }
    }
#pragma unroll
    for (int r = 0; r < 16; ++r) s0[r] = fexp2(s0[r] - m_run);
    const float p0 = (s0[0] + s0[1]) + (s0[2] + s0[3]);
    const float p1 = (s0[4] + s0[5]) + (s0[6] + s0[7]);
    const float p2 = (s0[8] + s0[9]) + (s0[10] + s0[11]);
    const float p3 = (s0[12] + s0[13]) + (s0[14] + s0[15]);
    l_run += (p0 + p1) + (p2 + p3);  // per-lane partial; combine at epilogue

#pragma unroll
    for (int ks = 0; ks < 2; ++ks) {
      const int rA = ks * 8;
      const int rB = ks * 8 + 4;
      const unsigned xA0 = cvtpk(s0[rA + 0], s0[rA + 1]);
      const unsigned xA1 = cvtpk(s0[rA + 2], s0[rA + 3]);
      const unsigned xB0 = cvtpk(s0[rB + 0], s0[rB + 1]);
      const unsigned xB1 = cvtpk(s0[rB + 2], s0[rB + 3]);
      const unsigned pA0 = (unsigned)__shfl_xor((int)xA0, 32);
      const unsigned pA1 = (unsigned)__shfl_xor((int)xA1, 32);
      const unsigned pB0 = (unsigned)__shfl_xor((int)xB0, 32);
      const unsigned pB1 = (unsigned)__shfl_xor((int)xB1, 32);
      u32x4 paw;
      paw[0] = hh ? pB0 : xA0;
      paw[1] = hh ? pB1 : xA1;
      paw[2] = hh ? xB0 : pA0;
      paw[3] = hh ? xB1 : pA1;
      const short8 pa = *(const short8*)&paw;
      __builtin_amdgcn_s_setprio(1);
#pragma unroll
      for (int db = 0; db < 4; ++db) {
        const int d = db * 32 + l31;
        const int r = d & 63;
        const int cl = ks * 32 + hh * 16 + ((d >> 6) << 6);
        const short8 vb = *(const short8*)(Vb + r * 128 + (cl ^ ((r & 7) << 4)));
        oa[db] = __builtin_amdgcn_mfma_f32_32x32x16_bf16(pa, vb, oa[db], 0, 0, 0);
      }
      __builtin_amdgcn_s_setprio(0);
    }
  }

  l_run += __shfl_xor(l_run, 32);  // deferred cross-half combine
  const float linv = 1.f / l_run;
#pragma unroll
  for (int r = 0; r < 16; ++r) {
    const int crow = (r & 3) + 8 * (r >> 2) + 4 * hh;
    const float inv = __shfl(linv, crow);
    u16* op = Obf + (size_t)(b * S_SZ + qt * 128 + w * 32 + crow) * (H_SZ * D_SZ) +
              h * D_SZ + l31;
#pragma unroll
    for (int db = 0; db < 4; ++db) op[db * 32] = f2bf(oa[db][r] * inv);
  }
}

// ---------------------------------------------------------------------------
extern "C" void kernel_launch(void* const* d_in, const int* in_sizes, int n_in,
                              void* d_out, int out_size, void* d_ws,
                              size_t ws_size, hipStream_t stream) {
  const float* hidden = (const float*)d_in[0];
  const float* fcos = (const float*)d_in[1];
  const float* fsin = (const float*)d_in[2];
  const float* w_q = (const float*)d_in[3];
  const float* w_k = (const float*)d_in[4];
  const float* w_v = (const float*)d_in[5];
  const float* w_o = (const float*)d_in[6];
  const float* ln_q_w = (const float*)d_in[7];
  const float* ln_q_b = (const float*)d_in[8];
  const float* ln_k_w = (const float*)d_in[9];
  const float* ln_k_b = (const float*)d_in[10];
  float* out = (float*)d_out;

  const int M = B_SZ * S_SZ;  // 4096

  char* ws = (char*)d_ws;
  u16* hid_bf = (u16*)ws;                       // 25165824 B [aliased a_bf]
  u16* wqt = (u16*)(ws + 25165824);             // 18874368 B [reused: w_o^T]
  u16* wkvt = (u16*)(ws + 44040192);            //  1572864 B (contiguous w/ wqt)
  float* kv_buf = (float*)(ws + 45613056);      //  4194304 B
  u16* k_bf = (u16*)(ws + 49807360);            //  1048576 B
  u16* vt_bf = (u16*)(ws + 50855936);           //  1048576 B (V^T [B][128][S])
  u16* a_bf = hid_bf;   // attn out reuses hid_bf (dead after qkv GEMM)
  float* q_f32 = out;   // fp32 q projection lives in d_out until attn

  conv_bf16<<<(M * DIM_SZ) / 2048, 256, 0, stream>>>(hidden, hid_bf, M * DIM_SZ);
  transpose_bf16<<<dim3(DIM_SZ / 32, DIM_SZ / 32), 256, 0, stream>>>(
      w_q, wqt, DIM_SZ, DIM_SZ);
  transpose_bf16<<<dim3(D_SZ / 32, DIM_SZ / 32), 256, 0, stream>>>(
      w_k, wkvt, DIM_SZ, D_SZ);
  transpose_bf16<<<dim3(D_SZ / 32, DIM_SZ / 32), 256, 0, stream>>>(
      w_v, wkvt + (size_t)D_SZ * DIM_SZ, DIM_SZ, D_SZ);

  // fused q+kv projection: Bt = [w_q^T | w_k^T | w_v^T], N=3328;
  // cols < 3072 -> q_f32, cols >= 3072 -> kv_buf.  grid 16x13=208 (%8==0).
  gemm256<<<(M / 256) * (3328 / 256), 512, 0, stream>>>(
      hid_bf, wqt, q_f32, kv_buf, M, 3328, DIM_SZ, DIM_SZ);
  transpose_bf16<<<dim3(DIM_SZ / 32, DIM_SZ / 32), 256, 0, stream>>>(
      w_o, wqt, DIM_SZ, DIM_SZ);

  // k-path LN+RoPE (q-path is fused into the attention kernel)
  ln_rope<<<M, 128, 0, stream>>>(kv_buf, 256, k_bf, ln_k_w, ln_k_b, fcos, fsin,
                                 1, 1.0f);
  transpose_v<<<dim3(S_SZ / 32, D_SZ / 32, B_SZ), 256, 0, stream>>>(kv_buf,
                                                                    vt_bf);

  attn_mfma32<<<B_SZ * H_SZ * 16, 256, 0, stream>>>(
      q_f32, k_bf, vt_bf, ln_q_w, ln_q_b, fcos, fsin, a_bf);

  // output projection: 256x192 tiles -> grid 16x16 = 256 blocks.
  gemm192<<<(M / 256) * (DIM_SZ / 192), 512, 0, stream>>>(a_bf, wqt, out, M,
                                                          DIM_SZ, DIM_SZ);
}